// Round 1
// baseline (45.700 us; speedup 1.0000x reference)
//
#include <hip/hip_runtime.h>
#include <hip/hip_bf16.h>

#define OBS_DIM 99
#define CH      128
#define HID     256
#define BPB     16    // batch items per block

__device__ __forceinline__ float dot4(float4 a, float4 b) {
    return a.x * b.x + a.y * b.y + a.z * b.z + a.w * b.w;
}

__global__ __launch_bounds__(256) void gnn_fused(
    const float* __restrict__ obs,      // (B, 99)
    const float* __restrict__ W_fgn,    // (4, 512)
    const float* __restrict__ b_fgn,    // (512,)
    const float* __restrict__ W_root,   // (4, 128)
    const float* __restrict__ b_conv,   // (128,)
    const float* __restrict__ attn_k,   // (128,)
    const float* __restrict__ W_dense,  // (128, 256)
    const float* __restrict__ b_dense,  // (256,)
    float* __restrict__ out)            // (B, 256)
{
    __shared__ __align__(16) float lobs[BPB][96];    // X(16) | A(16) | E(64)
    __shared__ __align__(16) float lpool[BPB][CH];
    __shared__ float lwp[4][4];                      // per-wave logit partials

    const int tid = threadIdx.x;
    const int b0  = blockIdx.x * BPB;

    // ---- stage observations (cols 3..98 of each of 16 rows) ----
    for (int i = tid; i < BPB * 96; i += 256) {
        int bi = i / 96, col = i - bi * 96;
        lobs[bi][col] = obs[(size_t)(b0 + bi) * OBS_DIM + 3 + col];
    }

    // ---- per-channel weights into registers (c fixed for all of phase 1) ----
    const int c = tid & 127;
    float4 Wf4[4];
    #pragma unroll
    for (int e = 0; e < 4; ++e)
        Wf4[e] = *reinterpret_cast<const float4*>(&W_fgn[e * 512 + c * 4]);
    const float4 bf4 = *reinterpret_cast<const float4*>(&b_fgn[c * 4]);
    float Wr[4];
    #pragma unroll
    for (int f = 0; f < 4; ++f) Wr[f] = W_root[f * CH + c];
    const float bconv = b_conv[c];
    const float ak    = attn_k[c];

    const int half = tid >> 7;   // which batch item of the pair
    const int wid  = tid >> 6;   // wave id 0..3
    const int lane = tid & 63;

    __syncthreads();

    // ---- phase 1: graph conv + attention pooling, 2 batch items per pass ----
    #pragma unroll 1
    for (int p = 0; p < BPB / 2; ++p) {
        const int bi = p * 2 + half;

        float4 X4[4];
        #pragma unroll
        for (int s = 0; s < 4; ++s)
            X4[s] = *reinterpret_cast<const float4*>(&lobs[bi][s * 4]);

        // G[s][e] = sum_f W_fgn[e, c*4+f] * X[s,f];  xb[s] = sum_f b_fgn[c*4+f]*X[s,f]
        float G[4][4], xb[4];
        #pragma unroll
        for (int s = 0; s < 4; ++s) {
            #pragma unroll
            for (int e = 0; e < 4; ++e) G[s][e] = dot4(Wf4[e], X4[s]);
            xb[s] = dot4(bf4, X4[s]);
        }

        float xc[4], pt[4];
        #pragma unroll
        for (int t = 0; t < 4; ++t) {
            const float4 A4 = *reinterpret_cast<const float4*>(&lobs[bi][16 + t * 4]);
            float m = 0.f;
            #pragma unroll
            for (int s = 0; s < 4; ++s) {
                const float4 E4 = *reinterpret_cast<const float4*>(&lobs[bi][32 + (t * 4 + s) * 4]);
                float inner = xb[s] + E4.x * G[s][0] + E4.y * G[s][1]
                                    + E4.z * G[s][2] + E4.w * G[s][3];
                const float a = (s == 0) ? A4.x : (s == 1) ? A4.y : (s == 2) ? A4.z : A4.w;
                m = fmaf(a, inner, m);
            }
            const float xr = X4[t].x * Wr[0] + X4[t].y * Wr[1]
                           + X4[t].z * Wr[2] + X4[t].w * Wr[3];
            const float v = m + xr + bconv;
            xc[t] = v > 0.f ? v : 0.f;
            pt[t] = xc[t] * ak;
        }

        // logits: reduce pt[t] over 128 channels = 2 waves
        #pragma unroll
        for (int st = 1; st < 64; st <<= 1) {
            #pragma unroll
            for (int t = 0; t < 4; ++t)
                pt[t] += __shfl_xor(pt[t], st, 64);
        }
        if (lane == 0) {
            #pragma unroll
            for (int t = 0; t < 4; ++t) lwp[wid][t] = pt[t];
        }
        __syncthreads();

        float l[4];
        #pragma unroll
        for (int t = 0; t < 4; ++t) l[t] = lwp[half * 2][t] + lwp[half * 2 + 1][t];
        const float mx = fmaxf(fmaxf(l[0], l[1]), fmaxf(l[2], l[3]));
        const float e0 = __expf(l[0] - mx), e1 = __expf(l[1] - mx);
        const float e2 = __expf(l[2] - mx), e3 = __expf(l[3] - mx);
        const float inv = 1.f / (e0 + e1 + e2 + e3);
        lpool[bi][c] = (e0 * xc[0] + e1 * xc[1] + e2 * xc[2] + e3 * xc[3]) * inv;
        __syncthreads();   // protects lwp reuse next iter & lpool for phase 2
    }

    // ---- phase 2: pooled @ W_dense + b_dense, tanh ----
    // thread -> h in [hq*4, hq*4+4), bi in [bq*4, bq*4+4)
    const int hq = tid & 63;
    const int bq = tid >> 6;
    float acc[4][4];
    #pragma unroll
    for (int j = 0; j < 4; ++j)
        #pragma unroll
        for (int i = 0; i < 4; ++i) acc[j][i] = 0.f;

    #pragma unroll 2
    for (int cc = 0; cc < CH; cc += 4) {
        float4 pv[4], w[4];
        #pragma unroll
        for (int j = 0; j < 4; ++j)
            pv[j] = *reinterpret_cast<const float4*>(&lpool[bq * 4 + j][cc]);
        #pragma unroll
        for (int k = 0; k < 4; ++k)
            w[k] = *reinterpret_cast<const float4*>(&W_dense[(size_t)(cc + k) * HID + hq * 4]);
        #pragma unroll
        for (int j = 0; j < 4; ++j) {
            const float pj[4] = {pv[j].x, pv[j].y, pv[j].z, pv[j].w};
            #pragma unroll
            for (int k = 0; k < 4; ++k) {
                acc[j][0] = fmaf(pj[k], w[k].x, acc[j][0]);
                acc[j][1] = fmaf(pj[k], w[k].y, acc[j][1]);
                acc[j][2] = fmaf(pj[k], w[k].z, acc[j][2]);
                acc[j][3] = fmaf(pj[k], w[k].w, acc[j][3]);
            }
        }
    }

    const float4 bd = *reinterpret_cast<const float4*>(&b_dense[hq * 4]);
    #pragma unroll
    for (int j = 0; j < 4; ++j) {
        float4 o;
        o.x = tanhf(acc[j][0] + bd.x);
        o.y = tanhf(acc[j][1] + bd.y);
        o.z = tanhf(acc[j][2] + bd.z);
        o.w = tanhf(acc[j][3] + bd.w);
        *reinterpret_cast<float4*>(&out[(size_t)(b0 + bq * 4 + j) * HID + hq * 4]) = o;
    }
}

extern "C" void kernel_launch(void* const* d_in, const int* in_sizes, int n_in,
                              void* d_out, int out_size, void* d_ws, size_t ws_size,
                              hipStream_t stream) {
    const float* obs     = (const float*)d_in[0];
    const float* W_fgn   = (const float*)d_in[1];
    const float* b_fgn   = (const float*)d_in[2];
    const float* W_root  = (const float*)d_in[3];
    const float* b_conv  = (const float*)d_in[4];
    const float* attn_k  = (const float*)d_in[5];
    const float* W_dense = (const float*)d_in[6];
    const float* b_dense = (const float*)d_in[7];
    float* out = (float*)d_out;

    const int Bn   = in_sizes[0] / OBS_DIM;   // 16384
    const int grid = Bn / BPB;                // 1024 (exact)
    gnn_fused<<<grid, 256, 0, stream>>>(obs, W_fgn, b_fgn, W_root, b_conv,
                                        attn_k, W_dense, b_dense, out);
}